// Round 2
// baseline (180.294 us; speedup 1.0000x reference)
//
#include <hip/hip_runtime.h>
#include <hip/hip_bf16.h>
#include <stdint.h>

// Problem constants
#define BB      131072
#define D_IN    100
#define HN      50
#define TT      100
#define TM1     99
#define DT_C    0.01f
#define GAMMA_C 0.05f
#define I0_C    0.12f

// LDS layout (floats). Rows padded 50->52 so every row is 16B-aligned.
// W0 stored TRANSPOSED: W0T[i][j] = W0[j][i], rows i=0..99 of length 52.
#define W0TOFF  0        // 100*52 = 5200
#define B0OFF   5200     // 50
#define W1OFF   5252     // 50*52 = 2600 (row-major [j][i])
#define B1OFF   7852     // 50
#define W2OFF   7904     // 99*52 = 5148 (row-major [k][i])
#define B2OFF   13052    // 99
#define LDSN    13152    // 52,608 bytes -> 2 blocks/CU

__global__ __launch_bounds__(256, 2) void net_kernel(
    const float* __restrict__ x,
    const float* __restrict__ W0,
    const float* __restrict__ b0,
    const float* __restrict__ W1,
    const float* __restrict__ b1,
    const float* __restrict__ W2,
    const float* __restrict__ b2,
    float* __restrict__ out)
{
    __shared__ __align__(16) float lds[LDSN];
    const int tid = threadIdx.x;

    // ---- Stage weights into LDS, one-time cost per block ----
    for (int idx = tid; idx < 5000; idx += 256) {       // W0 [50][100] -> W0T [100][52]
        int j = idx / 100, i = idx % 100;
        lds[W0TOFF + i * 52 + j] = W0[idx];
    }
    for (int idx = tid; idx < 50; idx += 256) lds[B0OFF + idx] = b0[idx];
    for (int idx = tid; idx < 2500; idx += 256) {       // W1 [50][50] -> [50][52]
        int j = idx / 50, i = idx % 50;
        lds[W1OFF + j * 52 + i] = W1[idx];
    }
    for (int idx = tid; idx < 50; idx += 256) lds[B1OFF + idx] = b1[idx];
    for (int idx = tid; idx < 4950; idx += 256) {       // W2 [99][50] -> [99][52]
        int k = idx / 50, i = idx % 50;
        lds[W2OFF + k * 52 + i] = W2[idx];
    }
    for (int idx = tid; idx < 99; idx += 256) lds[B2OFF + idx] = b2[idx];
    __syncthreads();

    const int b = blockIdx.x * 256 + tid;

    // ---- Layer 0: h0 = relu(x @ W0^T + b0). Stream x, 50 static accumulators ----
    float acc[HN];
    #pragma unroll
    for (int j = 0; j < HN; ++j) acc[j] = lds[B0OFF + j];

    const float4* xr = reinterpret_cast<const float4*>(x + (size_t)b * D_IN); // 400B rows, 16B aligned
    #pragma unroll 2
    for (int i4 = 0; i4 < 25; ++i4) {
        float4 xv = xr[i4];
        float xf[4] = { xv.x, xv.y, xv.z, xv.w };
        #pragma unroll
        for (int r = 0; r < 4; ++r) {
            const float xi = xf[r];
            const float* wrow = &lds[W0TOFF + (4 * i4 + r) * 52];
            #pragma unroll
            for (int q = 0; q < 12; ++q) {
                float4 w = *(const float4*)&wrow[4 * q];
                acc[4 * q + 0] = fmaf(xi, w.x, acc[4 * q + 0]);
                acc[4 * q + 1] = fmaf(xi, w.y, acc[4 * q + 1]);
                acc[4 * q + 2] = fmaf(xi, w.z, acc[4 * q + 2]);
                acc[4 * q + 3] = fmaf(xi, w.w, acc[4 * q + 3]);
            }
            float2 w2v = *(const float2*)&wrow[48];
            acc[48] = fmaf(xi, w2v.x, acc[48]);
            acc[49] = fmaf(xi, w2v.y, acc[49]);
        }
    }

    float h0[HN];
    #pragma unroll
    for (int j = 0; j < HN; ++j) h0[j] = fmaxf(acc[j], 0.0f);

    // ---- Layer 1: h1 = relu(h0 @ W1^T + b1). Fully unrolled (static reg indexing) ----
    float h1[HN];
    #pragma unroll
    for (int j = 0; j < HN; ++j) {
        const float* wrow = &lds[W1OFF + j * 52];
        float s0 = lds[B1OFF + j], s1 = 0.f, s2 = 0.f, s3 = 0.f;
        #pragma unroll
        for (int q = 0; q < 12; ++q) {
            float4 w = *(const float4*)&wrow[4 * q];
            s0 = fmaf(h0[4 * q + 0], w.x, s0);
            s1 = fmaf(h0[4 * q + 1], w.y, s1);
            s2 = fmaf(h0[4 * q + 2], w.z, s2);
            s3 = fmaf(h0[4 * q + 3], w.w, s3);
        }
        float2 w2v = *(const float2*)&wrow[48];
        s0 = fmaf(h0[48], w2v.x, s0);
        s1 = fmaf(h0[49], w2v.y, s1);
        h1[j] = fmaxf((s0 + s2) + (s1 + s3), 0.0f);
    }

    // ---- Layer 2 + Euler recurrence, fused. out_k = h1 . W2[k] + b2[k] ----
    auto dotW2 = [&](int k) -> float {
        const float* wrow = &lds[W2OFF + k * 52];
        float s0 = lds[B2OFF + k], s1 = 0.f, s2 = 0.f, s3 = 0.f;
        #pragma unroll
        for (int q = 0; q < 12; ++q) {
            float4 w = *(const float4*)&wrow[4 * q];
            s0 = fmaf(h1[4 * q + 0], w.x, s0);
            s1 = fmaf(h1[4 * q + 1], w.y, s1);
            s2 = fmaf(h1[4 * q + 2], w.z, s2);
            s3 = fmaf(h1[4 * q + 3], w.w, s3);
        }
        float2 w2v = *(const float2*)&wrow[48];
        s0 = fmaf(h1[48], w2v.x, s0);
        s1 = fmaf(h1[49], w2v.y, s1);
        return (s0 + s2) + (s1 + s3);
    };

    float2* orow = reinterpret_cast<float2*>(out + (size_t)b * TT); // 400B rows, 8B aligned

    float a = I0_C; // I[0]
    #pragma unroll 1
    for (int p = 0; p < 49; ++p) {
        float o1 = dotW2(2 * p);
        float bv = a + DT_C * (o1 * a * (1.0f - a) - GAMMA_C * a);   // I[2p+1]
        orow[p] = make_float2(a, bv);                                 // store I[2p], I[2p+1]
        float o2 = dotW2(2 * p + 1);
        a = bv + DT_C * (o2 * bv * (1.0f - bv) - GAMMA_C * bv);       // I[2p+2]
    }
    {
        float o1 = dotW2(98);
        float bv = a + DT_C * (o1 * a * (1.0f - a) - GAMMA_C * a);    // I[99]
        orow[49] = make_float2(a, bv);                                // store I[98], I[99]
    }
}

extern "C" void kernel_launch(void* const* d_in, const int* in_sizes, int n_in,
                              void* d_out, int out_size, void* d_ws, size_t ws_size,
                              hipStream_t stream) {
    const float* x  = (const float*)d_in[0];
    const float* W0 = (const float*)d_in[1];
    const float* b0 = (const float*)d_in[2];
    const float* W1 = (const float*)d_in[3];
    const float* b1 = (const float*)d_in[4];
    const float* W2 = (const float*)d_in[5];
    const float* b2 = (const float*)d_in[6];
    float* out = (float*)d_out;

    net_kernel<<<dim3(BB / 256), dim3(256), 0, stream>>>(x, W0, b0, W1, b1, W2, b2, out);
}